// Round 2
// baseline (508.623 us; speedup 1.0000x reference)
//
#include <hip/hip_runtime.h>
#include <math.h>

typedef unsigned short u16;
typedef _Float16 f16;
typedef __attribute__((ext_vector_type(8))) _Float16 f16x8;
typedef __attribute__((ext_vector_type(4))) float f32x4;

#define N_ROWS 131072
#define HID 128
#define WS_CH 8192                    // u16 per packed (layer,chunk) region: [hi|lo][nt][lane][c]
#define N_WCH 72                      // 2 layers * 36 chunks
#define N_PCH 8                       // 2 halves * 4 k-chunks of protos

// ---------------------------------------------------------------------------
// f16 split-2: v ≈ hi + lo with |v - hi - lo| <= 2^-22 |v|  (fp32-grade)
__device__ __forceinline__ void f16_split(float v, f16& hi, f16& lo) {
    f16 h = (f16)v;
    hi = h;
    lo = (f16)(v - (float)h);
}

// cardinal cubic B-spline on uniform knots g[j] = (j-3)*0.4 - 1 -> 8 coef slots
__device__ __forceinline__ void spline8(float xv, float* a8) {
    float s  = (xv + 2.2f) * 2.5f;
    float tf = floorf(s);
    int   tt = (int)tf;
    bool valid = (tt >= 0) && (tt <= 10);
    float kt = (float)(tt - 3) * 0.4f - 1.0f;
    float u  = (xv - kt) * 2.5f;
    float u2 = u * u, u3 = u2 * u;
    float om = 1.0f - u;
    float b3 = u3 * (1.0f / 6.0f);                                   // slot tt
    float b2 = (-3.f * u3 + 3.f * u2 + 3.f * u + 1.f) * (1.0f / 6.0f); // tt-1
    float b1 = (3.f * u3 - 6.f * u2 + 4.f) * (1.0f / 6.0f);          // tt-2
    float b0 = om * om * om * (1.0f / 6.0f);                         // tt-3
    #pragma unroll
    for (int c = 0; c < 8; ++c) {
        int d = tt - c;
        float v = 0.f;
        v = (d == 0) ? b3 : v;
        v = (d == 1) ? b2 : v;
        v = (d == 2) ? b1 : v;
        v = (d == 3) ? b0 : v;
        a8[c] = valid ? v : 0.f;
    }
}

// ---------------------------------------------------------------------------
// Pre-pack: weights (spline_w*scaler folded) and protos -> f16 hi/lo in MFMA
// B-fragment order. ws region r (u16 stride WS_CH):
//   r = l*36 + ch           : layer weights, B[k_local][o]
//   r = 72 + half*4 + kc    : protos,       B[k_local][p_local]
// in-region: idx = (nt*64 + kq*16 + n)*8 + c ; hi at +0, lo at +4096.
// ---------------------------------------------------------------------------
__global__ __launch_bounds__(256)
void pack_weights(const float* __restrict__ bw1, const float* __restrict__ sw1,
                  const float* __restrict__ sc1,
                  const float* __restrict__ bw2, const float* __restrict__ sw2,
                  const float* __restrict__ sc2,
                  const float* __restrict__ protos, u16* __restrict__ ws)
{
    int gid = blockIdx.x * 256 + threadIdx.x;
    if (gid < N_WCH * 4096) {
        int l  = gid / (36 * 4096);
        int r  = gid % (36 * 4096);
        int ch = r / 4096;
        int e  = r % 4096;             // o*32 + k_local
        int o  = e >> 5;
        int kl = e & 31;
        const float* bw = l ? bw2 : bw1;
        const float* sw = l ? sw2 : sw1;
        const float* sc = l ? sc2 : sc1;
        float v;
        if (ch < 4) {
            v = bw[o * HID + ch * 32 + kl];
        } else {
            int i = (ch - 4) * 4 + (kl >> 3);
            v = sw[(o * HID + i) * 8 + (kl & 7)] * sc[o * HID + i];
        }
        f16 hi, lo; f16_split(v, hi, lo);
        int nt = o >> 4, n = o & 15, kq = kl >> 3, c = kl & 7;
        size_t base = (size_t)(l * 36 + ch) * WS_CH;
        size_t idx  = ((size_t)nt * 64 + kq * 16 + n) * 8 + c;
        ws[base + idx]        = __builtin_bit_cast(u16, hi);
        ws[base + 4096 + idx] = __builtin_bit_cast(u16, lo);
    } else if (gid < (N_WCH + N_PCH) * 4096) {
        int r  = gid - N_WCH * 4096;
        int hk = r / 4096;             // half*4 + kc
        int e  = r % 4096;             // p_local*32 + kl
        int pl = e >> 5;
        int kl = e & 31;
        int half = hk >> 2, kc = hk & 3;
        float v = protos[(size_t)(half * 128 + pl) * HID + kc * 32 + kl];
        f16 hi, lo; f16_split(v, hi, lo);
        int nt = pl >> 4, n = pl & 15, kq = kl >> 3, c = kl & 7;
        size_t base = (size_t)(N_WCH + hk) * WS_CH;
        size_t idx  = ((size_t)nt * 64 + kq * 16 + n) * 8 + c;
        ws[base + idx]        = __builtin_bit_cast(u16, hi);
        ws[base + 4096 + idx] = __builtin_bit_cast(u16, lo);
    }
}

// ---------------------------------------------------------------------------
// Fused main kernel: x -> KAN layer1 -> KAN layer2 -> emb -> cosine argmax.
// Per block: 64 rows. Per wave: 16 rows; 16x16x32 f16 MFMA, 3-product split
// (ah*bh + al*bh + ah*bl); dropped al*bl term <= 2^-22 relative.
//
// B-fragments are read DIRECTLY from L2 into registers (wpack = 1.3 MB,
// resident in every XCD's L2; per-lane 16B loads are fully coalesced).
// No LDS staging, no Bfrag, and ZERO barriers in the hot loop:
// the t tile is wave-private end-to-end (x-stage rows tid>>2, A-read rows
// w*16+m, C-write rows w*16+q*4+r, emb rows tid>>2 all live in wave w's
// 16-row band). The single __syncthreads covers only rnp.
// L2 latency cover: first 8 fragments issued before A-prep (~300 VALU cyc),
// second 8 prefetched under the first 4 nt-tiles' MFMAs; LDS drop
// (51200 -> 34816 B) gives 4 blocks/CU for extra TLP.
// ---------------------------------------------------------------------------
__global__ __launch_bounds__(256, 4)
void kan_fused(const float* __restrict__ x, const float* __restrict__ protos,
               const u16* __restrict__ wpack,
               float* __restrict__ emb_out, float* __restrict__ assign_out)
{
    __shared__ float t[64][132];          // x -> h -> emb tile
    __shared__ float rnp[256];

    const int tid  = threadIdx.x;
    const int lane = tid & 63;
    const int w    = tid >> 6;            // wave 0..3
    const int m    = lane & 15;           // A-row / B-col within 16-tile
    const int q    = lane >> 4;           // 0..3
    const int row  = w * 16 + m;          // row within 64-row block tile
    const int brow = blockIdx.x * 64;

    // ---- proto inverse norms (one proto per thread) ----
    {
        const float4* pr = (const float4*)(protos + (size_t)tid * HID);
        float s = 0.0f;
        #pragma unroll
        for (int j = 0; j < 32; ++j) {
            float4 v = pr[j];
            s += v.x * v.x + v.y * v.y + v.z * v.z + v.w * v.w;
        }
        rnp[tid] = 1.0f / fmaxf(sqrtf(s), 1e-8f);
    }

    // ---- stage x tile (wave-private: wave w stages rows w*16..w*16+15) ----
    {
        const int m2 = tid >> 2, kq2 = tid & 3;
        const float4* src = (const float4*)(x + (size_t)(brow + m2) * HID + kq2 * 32);
        #pragma unroll
        for (int j = 0; j < 8; ++j) {
            float4 v = src[j];
            int k = kq2 * 32 + j * 4;
            t[m2][k] = v.x; t[m2][k + 1] = v.y; t[m2][k + 2] = v.z; t[m2][k + 3] = v.w;
        }
    }
    __syncthreads();   // rnp visibility only; t stays wave-private

    union { f16x8 v; f16 h[8]; } ah, al, bh, bl;
    f32x4 acc[8];
    const uint4* __restrict__ gb = (const uint4*)wpack + lane;  // per-lane base

    // ================= two KAN layers =================
    for (int l = 0; l < 2; ++l) {
        #pragma unroll
        for (int nt = 0; nt < 8; ++nt) acc[nt] = (f32x4){0.f, 0.f, 0.f, 0.f};

        for (int ch = 0; ch < 36; ++ch) {
            const uint4* rb = gb + (size_t)(l * 36 + ch) * 1024;
            uint4 b[16];   // b[2*nt]=hi, b[2*nt+1]=lo; fully static indexing

            // issue first-half B loads (nt 0..3) -> covered by A-prep VALU
            #pragma unroll
            for (int i = 0; i < 4; ++i) {
                b[2 * i]     = rb[i * 64];
                b[2 * i + 1] = rb[i * 64 + 512];
            }

            // ---- A fragment in registers ----
            float a8[8];
            if (ch < 4) {
                const float4* tr = (const float4*)&t[row][ch * 32 + q * 8];
                float4 v0 = tr[0], v1 = tr[1];
                float xs[8] = {v0.x, v0.y, v0.z, v0.w, v1.x, v1.y, v1.z, v1.w};
                #pragma unroll
                for (int j = 0; j < 8; ++j)    // silu via v_exp + v_rcp (~2^-22 rel)
                    a8[j] = xs[j] * __builtin_amdgcn_rcpf(1.0f + __expf(-xs[j]));
            } else {
                spline8(t[row][(ch - 4) * 4 + q], a8);   // feature i0+q, 8 coefs
            }
            #pragma unroll
            for (int j = 0; j < 8; ++j) f16_split(a8[j], ah.h[j], al.h[j]);

            // ---- MFMAs: prefetch second half under first-half MFMAs ----
            #pragma unroll
            for (int nt = 0; nt < 8; ++nt) {
                if (nt < 4) {
                    b[8 + 2 * nt] = rb[(nt + 4) * 64];
                    b[9 + 2 * nt] = rb[(nt + 4) * 64 + 512];
                }
                bh.v = __builtin_bit_cast(f16x8, b[2 * nt]);
                bl.v = __builtin_bit_cast(f16x8, b[2 * nt + 1]);
                acc[nt] = __builtin_amdgcn_mfma_f32_16x16x32_f16(ah.v, bh.v, acc[nt], 0, 0, 0);
                acc[nt] = __builtin_amdgcn_mfma_f32_16x16x32_f16(al.v, bh.v, acc[nt], 0, 0, 0);
                acc[nt] = __builtin_amdgcn_mfma_f32_16x16x32_f16(ah.v, bl.v, acc[nt], 0, 0, 0);
            }
        }

        // ---- C/D -> t (col = lane&15, row = q*4 + reg); wave-private rows ----
        #pragma unroll
        for (int nt = 0; nt < 8; ++nt)
            #pragma unroll
            for (int r = 0; r < 4; ++r)
                t[w * 16 + q * 4 + r][nt * 16 + m] = acc[nt][r];
        // same-wave LDS program order: no barrier needed between layers
    }

    // ---- emb epilogue: coalesced global write from t (wave-private rows) ----
    {
        const int m2 = tid >> 2, kq2 = tid & 3;
        float* dst = emb_out + (size_t)(brow + m2) * HID + kq2 * 32;
        #pragma unroll
        for (int j = 0; j < 8; ++j)
            *(float4*)(dst + j * 4) = *(const float4*)&t[m2][kq2 * 32 + j * 4];
    }

    // ================= cosine-sim argmax =================
    // row-norm is a positive per-row scale -> argmax-invariant; apply rnp only.
    float best[4]; int bi[4];
    #pragma unroll
    for (int r = 0; r < 4; ++r) { best[r] = -3.402823466e+38f; bi[r] = 0; }

    for (int half = 0; half < 2; ++half) {
        #pragma unroll
        for (int nt = 0; nt < 8; ++nt) acc[nt] = (f32x4){0.f, 0.f, 0.f, 0.f};

        for (int kc = 0; kc < 4; ++kc) {
            const uint4* rb = gb + (size_t)(N_WCH + half * 4 + kc) * 1024;
            uint4 b[16];
            #pragma unroll
            for (int i = 0; i < 4; ++i) {
                b[2 * i]     = rb[i * 64];
                b[2 * i + 1] = rb[i * 64 + 512];
            }

            float a8[8];
            {
                const float4* tr = (const float4*)&t[row][kc * 32 + q * 8];
                float4 v0 = tr[0], v1 = tr[1];
                a8[0] = v0.x; a8[1] = v0.y; a8[2] = v0.z; a8[3] = v0.w;
                a8[4] = v1.x; a8[5] = v1.y; a8[6] = v1.z; a8[7] = v1.w;
            }
            #pragma unroll
            for (int j = 0; j < 8; ++j) f16_split(a8[j], ah.h[j], al.h[j]);

            #pragma unroll
            for (int nt = 0; nt < 8; ++nt) {
                if (nt < 4) {
                    b[8 + 2 * nt] = rb[(nt + 4) * 64];
                    b[9 + 2 * nt] = rb[(nt + 4) * 64 + 512];
                }
                bh.v = __builtin_bit_cast(f16x8, b[2 * nt]);
                bl.v = __builtin_bit_cast(f16x8, b[2 * nt + 1]);
                acc[nt] = __builtin_amdgcn_mfma_f32_16x16x32_f16(ah.v, bh.v, acc[nt], 0, 0, 0);
                acc[nt] = __builtin_amdgcn_mfma_f32_16x16x32_f16(al.v, bh.v, acc[nt], 0, 0, 0);
                acc[nt] = __builtin_amdgcn_mfma_f32_16x16x32_f16(ah.v, bl.v, acc[nt], 0, 0, 0);
            }
        }

        // ascending p within lane + strict '>' keeps FIRST max (np.argmax)
        #pragma unroll
        for (int nt = 0; nt < 8; ++nt) {
            int p = half * 128 + nt * 16 + m;
            float rp = rnp[p];
            #pragma unroll
            for (int r = 0; r < 4; ++r) {
                float v = acc[nt][r] * rp;
                if (v > best[r]) { best[r] = v; bi[r] = p; }
            }
        }
    }

    // reduce over the 16 lanes (cols) sharing each row; tie -> smaller index
    #pragma unroll
    for (int r = 0; r < 4; ++r) {
        #pragma unroll
        for (int off = 1; off < 16; off <<= 1) {
            float ov = __shfl_xor(best[r], off);
            int   oi = __shfl_xor(bi[r], off);
            if (ov > best[r] || (ov == best[r] && oi < bi[r])) { best[r] = ov; bi[r] = oi; }
        }
        if (m == 0)
            assign_out[(size_t)brow + w * 16 + q * 4 + r] = (float)bi[r];
    }
}

// ---------------------------------------------------------------------------
extern "C" void kernel_launch(void* const* d_in, const int* in_sizes, int n_in,
                              void* d_out, int out_size, void* d_ws, size_t ws_size,
                              hipStream_t stream) {
    (void)in_sizes; (void)n_in; (void)out_size; (void)ws_size;

    const float* x      = (const float*)d_in[0];
    const float* protos = (const float*)d_in[1];
    // d_in[2] = grid: uniform knots (j-3)*0.4 - 1, hardcoded
    const float* bw1 = (const float*)d_in[3];
    const float* sw1 = (const float*)d_in[4];
    const float* sc1 = (const float*)d_in[5];
    const float* bw2 = (const float*)d_in[6];
    const float* sw2 = (const float*)d_in[7];
    const float* sc2 = (const float*)d_in[8];

    float* out    = (float*)d_out;
    float* embp   = out;                             // (N,128)
    float* assign = out + (size_t)N_ROWS * HID;      // (N,) as float
    u16*   wpack  = (u16*)d_ws;                      // 1.31 MB packed fragments

    pack_weights<<<dim3((N_WCH + N_PCH) * 4096 / 256), dim3(256), 0, stream>>>(
        bw1, sw1, sc1, bw2, sw2, sc2, protos, wpack);
    kan_fused<<<dim3(N_ROWS / 64), dim3(256), 0, stream>>>(
        x, protos, wpack, embp, assign);
}

// Round 3
// 434.021 us; speedup vs baseline: 1.1719x; 1.1719x over previous
//
#include <hip/hip_runtime.h>
#include <math.h>

typedef unsigned short u16;
typedef _Float16 f16;
typedef __attribute__((ext_vector_type(8))) _Float16 f16x8;
typedef __attribute__((ext_vector_type(4))) float f32x4;

#define N_ROWS 131072
#define HID 128
#define WS_CH 8192                    // u16 per packed (layer,chunk) region: [hi|lo][nt][lane][c]
#define N_WCH 72                      // 2 layers * 36 chunks
#define N_PCH 8                       // 2 halves * 4 k-chunks of protos

// ---------------------------------------------------------------------------
// f16 split-2: v ≈ hi + lo with |v - hi - lo| <= 2^-22 |v|  (fp32-grade)
__device__ __forceinline__ void f16_split(float v, f16& hi, f16& lo) {
    f16 h = (f16)v;
    hi = h;
    lo = (f16)(v - (float)h);
}

// cardinal cubic B-spline on uniform knots g[j] = (j-3)*0.4 - 1 -> 8 coef slots
__device__ __forceinline__ void spline8(float xv, float* a8) {
    float s  = (xv + 2.2f) * 2.5f;
    float tf = floorf(s);
    int   tt = (int)tf;
    bool valid = (tt >= 0) && (tt <= 10);
    float kt = (float)(tt - 3) * 0.4f - 1.0f;
    float u  = (xv - kt) * 2.5f;
    float u2 = u * u, u3 = u2 * u;
    float om = 1.0f - u;
    float b3 = u3 * (1.0f / 6.0f);                                   // slot tt
    float b2 = (-3.f * u3 + 3.f * u2 + 3.f * u + 1.f) * (1.0f / 6.0f); // tt-1
    float b1 = (3.f * u3 - 6.f * u2 + 4.f) * (1.0f / 6.0f);          // tt-2
    float b0 = om * om * om * (1.0f / 6.0f);                         // tt-3
    #pragma unroll
    for (int c = 0; c < 8; ++c) {
        int d = tt - c;
        float v = 0.f;
        v = (d == 0) ? b3 : v;
        v = (d == 1) ? b2 : v;
        v = (d == 2) ? b1 : v;
        v = (d == 3) ? b0 : v;
        a8[c] = valid ? v : 0.f;
    }
}

#define GLOAD_LDS16(g, l)                                                         \
    __builtin_amdgcn_global_load_lds(                                             \
        (const __attribute__((address_space(1))) unsigned int*)(g),               \
        (__attribute__((address_space(3))) unsigned int*)(l), 16, 0, 0)

// t-tile XOR swizzle: slot (16B unit) within row XORed with row&31.
// Breaks the stride-128-float same-bank pattern at every access site (<=2-way).
__device__ __forceinline__ int tswz(int r, int c) {
    return (r << 7) + ((((c >> 2) ^ r) & 31) << 2) + (c & 3);
}

// ---------------------------------------------------------------------------
// Pre-pack: weights (spline_w*scaler folded) and protos -> f16 hi/lo in MFMA
// B-fragment order. Proto fragments are PRE-NORMALIZED (1/||p|| folded in),
// removing the rnp pass from the main kernel (argmax-invariant row scale).
// ws region r (u16 stride WS_CH):
//   r = l*36 + ch           : layer weights, B[k_local][o]
//   r = 72 + half*4 + kc    : normalized protos, B[k_local][p_local]
// in-region: idx = (nt*64 + kq*16 + n)*8 + c ; hi at +0, lo at +4096.
// ---------------------------------------------------------------------------
__global__ __launch_bounds__(256)
void pack_weights(const float* __restrict__ bw1, const float* __restrict__ sw1,
                  const float* __restrict__ sc1,
                  const float* __restrict__ bw2, const float* __restrict__ sw2,
                  const float* __restrict__ sc2,
                  const float* __restrict__ protos, u16* __restrict__ ws)
{
    int gid = blockIdx.x * 256 + threadIdx.x;
    if (gid < N_WCH * 4096) {
        int l  = gid / (36 * 4096);
        int r  = gid % (36 * 4096);
        int ch = r / 4096;
        int e  = r % 4096;             // o*32 + k_local
        int o  = e >> 5;
        int kl = e & 31;
        const float* bw = l ? bw2 : bw1;
        const float* sw = l ? sw2 : sw1;
        const float* sc = l ? sc2 : sc1;
        float v;
        if (ch < 4) {
            v = bw[o * HID + ch * 32 + kl];
        } else {
            int i = (ch - 4) * 4 + (kl >> 3);
            v = sw[(o * HID + i) * 8 + (kl & 7)] * sc[o * HID + i];
        }
        f16 hi, lo; f16_split(v, hi, lo);
        int nt = o >> 4, n = o & 15, kq = kl >> 3, c = kl & 7;
        size_t base = (size_t)(l * 36 + ch) * WS_CH;
        size_t idx  = ((size_t)nt * 64 + kq * 16 + n) * 8 + c;
        ws[base + idx]        = __builtin_bit_cast(u16, hi);
        ws[base + 4096 + idx] = __builtin_bit_cast(u16, lo);
    } else if (gid < (N_WCH + N_PCH) * 4096) {
        int r  = gid - N_WCH * 4096;
        int hk = r / 4096;             // half*4 + kc
        int e  = r % 4096;             // p_local*32 + kl
        int pl = e >> 5;
        int kl = e & 31;                // == lane&31 (regions are 64-aligned)
        int half = hk >> 2, kc = hk & 3;
        int p = half * 128 + pl;
        // cooperative ||proto_p||^2 over the 32-lane group owning proto p
        const float4 pv = *(const float4*)(protos + (size_t)p * HID + kl * 4);
        float s = pv.x * pv.x + pv.y * pv.y + pv.z * pv.z + pv.w * pv.w;
        #pragma unroll
        for (int off = 1; off < 32; off <<= 1) s += __shfl_xor(s, off);
        float rp = 1.0f / fmaxf(sqrtf(s), 1e-8f);
        float v = protos[(size_t)p * HID + kc * 32 + kl] * rp;
        f16 hi, lo; f16_split(v, hi, lo);
        int nt = pl >> 4, n = pl & 15, kq = kl >> 3, c = kl & 7;
        size_t base = (size_t)(N_WCH + hk) * WS_CH;
        size_t idx  = ((size_t)nt * 64 + kq * 16 + n) * 8 + c;
        ws[base + idx]        = __builtin_bit_cast(u16, hi);
        ws[base + 4096 + idx] = __builtin_bit_cast(u16, lo);
    }
}

// ---------------------------------------------------------------------------
// Fused main kernel: x -> KAN layer1 -> KAN layer2 -> emb -> cosine argmax.
// Per block: 64 rows, 4 waves; 16x16x32 f16 MFMA, 3-product split
// (ah*bh + al*bh + ah*bl); dropped al*bl term <= 2^-22 relative.
//
// Pipeline: full-chunk double-buffered Bfrag (2 x 16 KB) staged with
// global_load_lds. Per chunk: issue loads for chunk+1 into the idle buffer,
// A-prep + 24 MFMAs from the live buffer, then ONE vmcnt(0) + raw s_barrier
// (drain covered by the whole body; 81 barriers total vs 161 in R1).
// t is wave-private end-to-end (16-row bands), XOR-swizzled vs bank conflicts.
// LDS = 32 KB t + 32 KB Bfrag = 64 KB -> 2 blocks/CU.
// ---------------------------------------------------------------------------
__global__ __launch_bounds__(256, 2)
void kan_fused(const float* __restrict__ x, const u16* __restrict__ wpack,
               float* __restrict__ emb_out, float* __restrict__ assign_out)
{
    __shared__ float t[64 * 128];          // x -> h -> emb tile (swizzled)
    __shared__ u16   Bfrag[2][2][8][64][8]; // [buf][hi/lo][nt][lane][c]

    const int tid  = threadIdx.x;
    const int lane = tid & 63;
    const int w    = tid >> 6;            // wave 0..3
    const int m    = lane & 15;           // A-row / B-col within 16-tile
    const int q    = lane >> 4;           // 0..3
    const int row  = w * 16 + m;          // row within 64-row block tile
    const int brow = blockIdx.x * 64;

    // stage 16 KB region -> Bfrag[buf_] (wave w copies its 4 KB quarter)
#define STAGE(reg_, buf_) do {                                                     \
        const char* _g = (const char*)(wpack + (size_t)(reg_) * WS_CH)             \
                         + w * 4096 + (size_t)lane * 16;                           \
        char* _l = (char*)&Bfrag[(buf_)][0][0][0][0] + w * 4096;                   \
        GLOAD_LDS16(_g,        _l);                                                \
        GLOAD_LDS16(_g + 1024, _l + 1024);                                         \
        GLOAD_LDS16(_g + 2048, _l + 2048);                                         \
        GLOAD_LDS16(_g + 3072, _l + 3072);                                         \
    } while (0)

    // one barrier per chunk: drain this body's prefetch, sync, pin scheduler
#define CHUNK_BARRIER() do {                                                       \
        asm volatile("s_waitcnt vmcnt(0)" ::: "memory");                           \
        __builtin_amdgcn_s_barrier();                                              \
        __builtin_amdgcn_sched_barrier(0);                                         \
    } while (0)

    // prefetch chunk 0 immediately
    STAGE(0, 0);

    // ---- stage x tile (wave-private rows; swizzled) ----
    {
        const int m2 = tid >> 2, kq2 = tid & 3;
        const float4* src = (const float4*)(x + (size_t)(brow + m2) * HID + kq2 * 32);
        #pragma unroll
        for (int j = 0; j < 8; ++j) {
            float4 v = src[j];
            *(float4*)&t[tswz(m2, kq2 * 32 + j * 4)] = v;
        }
    }
    CHUNK_BARRIER();   // chunk 0 resident in Bfrag[0]

    union { f16x8 v; f16 h[8]; } ah, al, bh, bl;
    f32x4 acc[8];

    // ================= two KAN layers =================
    for (int l = 0; l < 2; ++l) {
        #pragma unroll
        for (int nt = 0; nt < 8; ++nt) acc[nt] = (f32x4){0.f, 0.f, 0.f, 0.f};

        for (int ch = 0; ch < 36; ++ch) {
            const int reg = l * 36 + ch;
            const int cur = reg & 1;
            STAGE(reg + 1, cur ^ 1);       // 71 -> 72 rolls into protos

            // ---- A fragment in registers ----
            float a8[8];
            if (ch < 4) {
                float4 v0 = *(const float4*)&t[tswz(row, ch * 32 + q * 8)];
                float4 v1 = *(const float4*)&t[tswz(row, ch * 32 + q * 8 + 4)];
                float xs[8] = {v0.x, v0.y, v0.z, v0.w, v1.x, v1.y, v1.z, v1.w};
                #pragma unroll
                for (int j = 0; j < 8; ++j)    // silu via v_exp + v_rcp (~2^-22 rel)
                    a8[j] = xs[j] * __builtin_amdgcn_rcpf(1.0f + __expf(-xs[j]));
            } else {
                spline8(t[tswz(row, (ch - 4) * 4 + q)], a8);   // feature i0+q
            }
            #pragma unroll
            for (int j = 0; j < 8; ++j) f16_split(a8[j], ah.h[j], al.h[j]);

            // ---- MFMAs: 8 col-tiles x 3 split products from live buffer ----
            #pragma unroll
            for (int nt = 0; nt < 8; ++nt) {
                bh.v = *(const f16x8*)Bfrag[cur][0][nt][lane];
                bl.v = *(const f16x8*)Bfrag[cur][1][nt][lane];
                acc[nt] = __builtin_amdgcn_mfma_f32_16x16x32_f16(ah.v, bh.v, acc[nt], 0, 0, 0);
                acc[nt] = __builtin_amdgcn_mfma_f32_16x16x32_f16(al.v, bh.v, acc[nt], 0, 0, 0);
                acc[nt] = __builtin_amdgcn_mfma_f32_16x16x32_f16(ah.v, bl.v, acc[nt], 0, 0, 0);
            }
            CHUNK_BARRIER();
        }

        // ---- C/D -> t (col = lane&15, row = q*4 + reg); wave-private rows ----
        #pragma unroll
        for (int nt = 0; nt < 8; ++nt)
            #pragma unroll
            for (int r = 0; r < 4; ++r)
                t[tswz(w * 16 + q * 4 + r, nt * 16 + m)] = acc[nt][r];
        // same-wave LDS program order: no barrier needed between layers
    }

    // ---- emb epilogue: coalesced global write from t (wave-private rows) ----
    {
        const int m2 = tid >> 2, kq2 = tid & 3;
        float* dst = emb_out + (size_t)(brow + m2) * HID + kq2 * 32;
        #pragma unroll
        for (int j = 0; j < 8; ++j)
            *(float4*)(dst + j * 4) = *(const float4*)&t[tswz(m2, kq2 * 32 + j * 4)];
    }

    // ================= cosine-sim argmax =================
    // proto fragments are pre-normalized; row norm is argmax-invariant.
    float best[4]; int bi[4];
    #pragma unroll
    for (int r = 0; r < 4; ++r) { best[r] = -3.402823466e+38f; bi[r] = 0; }

    for (int half = 0; half < 2; ++half) {
        #pragma unroll
        for (int nt = 0; nt < 8; ++nt) acc[nt] = (f32x4){0.f, 0.f, 0.f, 0.f};

        for (int kc = 0; kc < 4; ++kc) {
            const int reg = N_WCH + half * 4 + kc;
            const int cur = reg & 1;
            if (reg != 79) STAGE(reg + 1, cur ^ 1);

            float a8[8];
            {
                float4 v0 = *(const float4*)&t[tswz(row, kc * 32 + q * 8)];
                float4 v1 = *(const float4*)&t[tswz(row, kc * 32 + q * 8 + 4)];
                a8[0] = v0.x; a8[1] = v0.y; a8[2] = v0.z; a8[3] = v0.w;
                a8[4] = v1.x; a8[5] = v1.y; a8[6] = v1.z; a8[7] = v1.w;
            }
            #pragma unroll
            for (int j = 0; j < 8; ++j) f16_split(a8[j], ah.h[j], al.h[j]);

            #pragma unroll
            for (int nt = 0; nt < 8; ++nt) {
                bh.v = *(const f16x8*)Bfrag[cur][0][nt][lane];
                bl.v = *(const f16x8*)Bfrag[cur][1][nt][lane];
                acc[nt] = __builtin_amdgcn_mfma_f32_16x16x32_f16(ah.v, bh.v, acc[nt], 0, 0, 0);
                acc[nt] = __builtin_amdgcn_mfma_f32_16x16x32_f16(al.v, bh.v, acc[nt], 0, 0, 0);
                acc[nt] = __builtin_amdgcn_mfma_f32_16x16x32_f16(ah.v, bl.v, acc[nt], 0, 0, 0);
            }
            CHUNK_BARRIER();
        }

        // ascending p within lane + strict '>' keeps FIRST max (np.argmax)
        #pragma unroll
        for (int nt = 0; nt < 8; ++nt) {
            int p = half * 128 + nt * 16 + m;
            #pragma unroll
            for (int r = 0; r < 4; ++r) {
                float v = acc[nt][r];
                if (v > best[r]) { best[r] = v; bi[r] = p; }
            }
        }
    }

    // reduce over the 16 lanes (cols) sharing each row; tie -> smaller index
    #pragma unroll
    for (int r = 0; r < 4; ++r) {
        #pragma unroll
        for (int off = 1; off < 16; off <<= 1) {
            float ov = __shfl_xor(best[r], off);
            int   oi = __shfl_xor(bi[r], off);
            if (ov > best[r] || (ov == best[r] && oi < bi[r])) { best[r] = ov; bi[r] = oi; }
        }
        if (m == 0)
            assign_out[(size_t)brow + w * 16 + q * 4 + r] = (float)bi[r];
    }
#undef STAGE
#undef CHUNK_BARRIER
}

// ---------------------------------------------------------------------------
extern "C" void kernel_launch(void* const* d_in, const int* in_sizes, int n_in,
                              void* d_out, int out_size, void* d_ws, size_t ws_size,
                              hipStream_t stream) {
    (void)in_sizes; (void)n_in; (void)out_size; (void)ws_size;

    const float* x      = (const float*)d_in[0];
    const float* protos = (const float*)d_in[1];
    // d_in[2] = grid: uniform knots (j-3)*0.4 - 1, hardcoded
    const float* bw1 = (const float*)d_in[3];
    const float* sw1 = (const float*)d_in[4];
    const float* sc1 = (const float*)d_in[5];
    const float* bw2 = (const float*)d_in[6];
    const float* sw2 = (const float*)d_in[7];
    const float* sc2 = (const float*)d_in[8];

    float* out    = (float*)d_out;
    float* embp   = out;                             // (N,128)
    float* assign = out + (size_t)N_ROWS * HID;      // (N,) as float
    u16*   wpack  = (u16*)d_ws;                      // 1.31 MB packed fragments

    pack_weights<<<dim3((N_WCH + N_PCH) * 4096 / 256), dim3(256), 0, stream>>>(
        bw1, sw1, sc1, bw2, sw2, sc2, protos, wpack);
    kan_fused<<<dim3(N_ROWS / 64), dim3(256), 0, stream>>>(
        x, wpack, embp, assign);
}

// Round 5
// 398.174 us; speedup vs baseline: 1.2774x; 1.0900x over previous
//
#include <hip/hip_runtime.h>
#include <math.h>

typedef unsigned short u16;
typedef _Float16 f16;
typedef __attribute__((ext_vector_type(8))) _Float16 f16x8;
typedef __attribute__((ext_vector_type(2))) _Float16 f16x2;
typedef __attribute__((ext_vector_type(4))) float f32x4;

#define N_ROWS 131072
#define HID 128
#define WS_CH 8192                    // u16 per packed (layer,chunk) region: [hi|lo][nt][lane][c]
#define N_WCH 72                      // 2 layers * 36 chunks
#define N_PCH 8                       // 2 halves * 4 k-chunks of protos

// ---------------------------------------------------------------------------
// f16 split-2 of 8 values, packed: hi = RTZ(v) (11-bit significand, exact via
// mantissa mask), lo = RTZ(v - hi).  |v - hi - lo| <= ~2^-22 |v|.
// cvt_pkrtz packs 2 f32 -> 2 f16 in one VALU op (no scalar cvt + v_pack chains).
__device__ __forceinline__ void split8(const float* a8, f16x8& hv, f16x8& lv) {
    union { f16x8 v; f16x2 p[4]; } H, L;
    #pragma unroll
    for (int j = 0; j < 4; ++j) {
        float v0 = a8[2 * j], v1 = a8[2 * j + 1];
        float h0 = __builtin_bit_cast(float, __builtin_bit_cast(unsigned, v0) & 0xFFFFE000u);
        float h1 = __builtin_bit_cast(float, __builtin_bit_cast(unsigned, v1) & 0xFFFFE000u);
        H.p[j] = __builtin_bit_cast(f16x2, __builtin_amdgcn_cvt_pkrtz(v0, v1));           // (hi0,hi1) exactly
        L.p[j] = __builtin_bit_cast(f16x2, __builtin_amdgcn_cvt_pkrtz(v0 - h0, v1 - h1)); // residuals
    }
    hv = H.v; lv = L.v;
}

// cardinal cubic B-spline on uniform knots g[j] = (j-3)*0.4 - 1 -> 8 coef slots
__device__ __forceinline__ void spline8(float xv, float* a8) {
    float s  = (xv + 2.2f) * 2.5f;
    float tf = floorf(s);
    int   tt = (int)tf;
    bool valid = (tt >= 0) && (tt <= 10);
    float kt = (float)(tt - 3) * 0.4f - 1.0f;
    float u  = (xv - kt) * 2.5f;
    float u2 = u * u, u3 = u2 * u;
    float om = 1.0f - u;
    float b3 = u3 * (1.0f / 6.0f);                                   // slot tt
    float b2 = (-3.f * u3 + 3.f * u2 + 3.f * u + 1.f) * (1.0f / 6.0f); // tt-1
    float b1 = (3.f * u3 - 6.f * u2 + 4.f) * (1.0f / 6.0f);          // tt-2
    float b0 = om * om * om * (1.0f / 6.0f);                         // tt-3
    #pragma unroll
    for (int c = 0; c < 8; ++c) {
        int d = tt - c;
        float v = 0.f;
        v = (d == 0) ? b3 : v;
        v = (d == 1) ? b2 : v;
        v = (d == 2) ? b1 : v;
        v = (d == 3) ? b0 : v;
        a8[c] = valid ? v : 0.f;
    }
}

// t-tile XOR swizzle: slot (16B unit) within row XORed with row&31.
// Breaks the stride-128-float same-bank pattern at every access site (<=2-way).
__device__ __forceinline__ int tswz(int r, int c) {
    return (r << 7) + ((((c >> 2) ^ r) & 31) << 2) + (c & 3);
}

// ---------------------------------------------------------------------------
// Pre-pack: weights (spline_w*scaler folded) and protos -> f16 hi/lo in MFMA
// B-fragment order. Proto fragments are PRE-NORMALIZED (1/||p|| folded in),
// removing the rnp pass from the main kernel (argmax-invariant row scale).
// ws region r (u16 stride WS_CH):
//   r = l*36 + ch           : layer weights, B[k_local][o]
//   r = 72 + half*4 + kc    : normalized protos, B[k_local][p_local]
// in-region: idx = (nt*64 + kq*16 + n)*8 + c ; hi at +0, lo at +4096.
// Regions 0..79 are consumed strictly sequentially by kan_fused.
// ---------------------------------------------------------------------------
__global__ __launch_bounds__(256)
void pack_weights(const float* __restrict__ bw1, const float* __restrict__ sw1,
                  const float* __restrict__ sc1,
                  const float* __restrict__ bw2, const float* __restrict__ sw2,
                  const float* __restrict__ sc2,
                  const float* __restrict__ protos, u16* __restrict__ ws)
{
    int gid = blockIdx.x * 256 + threadIdx.x;
    if (gid < N_WCH * 4096) {
        int l  = gid / (36 * 4096);
        int r  = gid % (36 * 4096);
        int ch = r / 4096;
        int e  = r % 4096;             // o*32 + k_local
        int o  = e >> 5;
        int kl = e & 31;
        const float* bw = l ? bw2 : bw1;
        const float* sw = l ? sw2 : sw1;
        const float* sc = l ? sc2 : sc1;
        float v;
        if (ch < 4) {
            v = bw[o * HID + ch * 32 + kl];
        } else {
            int i = (ch - 4) * 4 + (kl >> 3);
            v = sw[(o * HID + i) * 8 + (kl & 7)] * sc[o * HID + i];
        }
        f16 hi = (f16)v;
        f16 lo = (f16)(v - (float)hi);
        int nt = o >> 4, n = o & 15, kq = kl >> 3, c = kl & 7;
        size_t base = (size_t)(l * 36 + ch) * WS_CH;
        size_t idx  = ((size_t)nt * 64 + kq * 16 + n) * 8 + c;
        ws[base + idx]        = __builtin_bit_cast(u16, hi);
        ws[base + 4096 + idx] = __builtin_bit_cast(u16, lo);
    } else if (gid < (N_WCH + N_PCH) * 4096) {
        int r  = gid - N_WCH * 4096;
        int hk = r / 4096;             // half*4 + kc
        int e  = r % 4096;             // p_local*32 + kl
        int pl = e >> 5;
        int kl = e & 31;                // == lane&31 (regions are 64-aligned)
        int half = hk >> 2, kc = hk & 3;
        int p = half * 128 + pl;
        // cooperative ||proto_p||^2 over the 32-lane group owning proto p
        const float4 pv = *(const float4*)(protos + (size_t)p * HID + kl * 4);
        float s = pv.x * pv.x + pv.y * pv.y + pv.z * pv.z + pv.w * pv.w;
        #pragma unroll
        for (int off = 1; off < 32; off <<= 1) s += __shfl_xor(s, off);
        float rp = 1.0f / fmaxf(sqrtf(s), 1e-8f);
        float v = protos[(size_t)p * HID + kc * 32 + kl] * rp;
        f16 hi = (f16)v;
        f16 lo = (f16)(v - (float)hi);
        int nt = pl >> 4, n = pl & 15, kq = kl >> 3, c = kl & 7;
        size_t base = (size_t)(N_WCH + hk) * WS_CH;
        size_t idx  = ((size_t)nt * 64 + kq * 16 + n) * 8 + c;
        ws[base + idx]        = __builtin_bit_cast(u16, hi);
        ws[base + 4096 + idx] = __builtin_bit_cast(u16, lo);
    }
}

// ---------------------------------------------------------------------------
// Fused main kernel: x -> KAN layer1 -> KAN layer2 -> emb -> cosine argmax.
// Per block: 64 rows, 4 waves; 16x16x32 f16 MFMA, 3-product split
// (ah*bh + al*bh + ah*bl); dropped al*bl term <= 2^-22 relative.
//
// Pipeline (R1-proven, tightened): B for chunk s+1 is loaded into REGISTERS
// during chunk s's epoch (loads in flight across both barriers, MFMA, and
// A-prep — L2 latency fully covered). Single 16 KB Bfrag buffer:
//   per epoch: A-prep | B1(lgkm0+bar) | ds_write staged regs | issue loads
//   for s+1 | B2(lgkm0+bar) | 24 MFMA (setprio-wrapped)
// LDS = 32 KB t (XOR-swizzled, wave-private rows) + 16 KB Bfrag = 48 KB
// -> 3 blocks/CU (12 waves). No rnp pass (protos pre-normalized in pack).
// ---------------------------------------------------------------------------
__global__ __launch_bounds__(256, 3)
void kan_fused(const float* __restrict__ x, const u16* __restrict__ wpack,
               float* __restrict__ emb_out, float* __restrict__ assign_out)
{
    __shared__ float t[64 * 128];          // x -> h -> emb tile (swizzled)
    __shared__ u16   Bfrag[2][8][64][8];   // [hi/lo][nt][lane(kq*16+n)][c]

    const int tid  = threadIdx.x;
    const int lane = tid & 63;
    const int w    = tid >> 6;            // wave 0..3
    const int m    = lane & 15;           // A-row / B-col within 16-tile
    const int q    = lane >> 4;           // 0..3
    const int row  = w * 16 + m;          // row within 64-row block tile
    const int brow = blockIdx.x * 64;

    // per-lane staging pointers (bump by 16 KB per region; imm offsets 0..3072)
    const char* gptr = (const char*)wpack + (size_t)w * 4096 + (size_t)lane * 16;
    uint4* const lptr = (uint4*)&Bfrag[0][0][0][0] + w * 256 + lane;
    uint4 rr0, rr1, rr2, rr3;             // one region in flight

#define ISSUE_LOADS() do {                                                         \
        rr0 = *(const uint4*)(gptr);                                               \
        rr1 = *(const uint4*)(gptr + 1024);                                        \
        rr2 = *(const uint4*)(gptr + 2048);                                        \
        rr3 = *(const uint4*)(gptr + 3072);                                        \
        gptr += 16384;                                                             \
    } while (0)

#define STORE_LDS() do {                                                           \
        lptr[0] = rr0; lptr[64] = rr1; lptr[128] = rr2; lptr[192] = rr3;           \
    } while (0)

    // raw barrier: drain own LDS ops, sync, pin scheduling.
    // NO vmcnt drain -> prefetched global loads survive across it.
#define PIPE_BARRIER() do {                                                        \
        asm volatile("s_waitcnt lgkmcnt(0)" ::: "memory");                         \
        __builtin_amdgcn_s_barrier();                                              \
        __builtin_amdgcn_sched_barrier(0);                                         \
    } while (0)

    ISSUE_LOADS();    // region 0 in flight ASAP

    // ---- stage x tile (wave-private rows; swizzled) ----
    {
        const int m2 = tid >> 2, kq2 = tid & 3;
        const float4* src = (const float4*)(x + (size_t)(brow + m2) * HID + kq2 * 32);
        #pragma unroll
        for (int j = 0; j < 8; ++j) {
            float4 v = src[j];
            *(float4*)&t[tswz(m2, kq2 * 32 + j * 4)] = v;
        }
    }
    // no barrier needed: t rows are wave-private; Bfrag handled by pipe barriers

    f16x8 ahv, alv, bhv, blv;
    f32x4 acc[8];

    // ================= two KAN layers =================
    for (int l = 0; l < 2; ++l) {
        #pragma unroll
        for (int nt = 0; nt < 8; ++nt) acc[nt] = (f32x4){0.f, 0.f, 0.f, 0.f};

        for (int ch = 0; ch < 36; ++ch) {
            // ---- A fragment in registers ----
            float a8[8];
            if (ch < 4) {
                float4 v0 = *(const float4*)&t[tswz(row, ch * 32 + q * 8)];
                float4 v1 = *(const float4*)&t[tswz(row, ch * 32 + q * 8 + 4)];
                float xs[8] = {v0.x, v0.y, v0.z, v0.w, v1.x, v1.y, v1.z, v1.w};
                #pragma unroll
                for (int j = 0; j < 8; ++j)    // silu via v_exp + v_rcp (~2^-22 rel)
                    a8[j] = xs[j] * __builtin_amdgcn_rcpf(1.0f + __expf(-xs[j]));
            } else {
                spline8(t[tswz(row, (ch - 4) * 4 + q)], a8);   // feature i0+q
            }
            split8(a8, ahv, alv);

            PIPE_BARRIER();     // B1: all waves done reading Bfrag(prev region)
            STORE_LDS();        // waits vmcnt for rr (issued a full epoch ago)
            ISSUE_LOADS();      // next region (71 -> 72 rolls into protos)
            PIPE_BARRIER();     // B2: all waves' ds_writes visible

            // ---- MFMAs: 8 col-tiles x 3 split products ----
            __builtin_amdgcn_s_setprio(1);
            #pragma unroll
            for (int nt = 0; nt < 8; ++nt) {
                bhv = *(const f16x8*)Bfrag[0][nt][lane];
                blv = *(const f16x8*)Bfrag[1][nt][lane];
                acc[nt] = __builtin_amdgcn_mfma_f32_16x16x32_f16(ahv, bhv, acc[nt], 0, 0, 0);
                acc[nt] = __builtin_amdgcn_mfma_f32_16x16x32_f16(alv, bhv, acc[nt], 0, 0, 0);
                acc[nt] = __builtin_amdgcn_mfma_f32_16x16x32_f16(ahv, blv, acc[nt], 0, 0, 0);
            }
            __builtin_amdgcn_s_setprio(0);
        }

        // ---- C/D -> t (col = lane&15, row = q*4 + reg); wave-private rows ----
        #pragma unroll
        for (int nt = 0; nt < 8; ++nt)
            #pragma unroll
            for (int r = 0; r < 4; ++r)
                t[tswz(w * 16 + q * 4 + r, nt * 16 + m)] = acc[nt][r];
        // same-wave LDS program order: no barrier needed between layers
    }

    // ---- emb epilogue: coalesced global write from t (wave-private rows) ----
    {
        const int m2 = tid >> 2, kq2 = tid & 3;
        float* dst = emb_out + (size_t)(brow + m2) * HID + kq2 * 32;
        #pragma unroll
        for (int j = 0; j < 8; ++j)
            *(float4*)(dst + j * 4) = *(const float4*)&t[tswz(m2, kq2 * 32 + j * 4)];
    }

    // ================= cosine-sim argmax =================
    // proto fragments are pre-normalized; row norm is argmax-invariant.
    float best[4]; int bi[4];
    #pragma unroll
    for (int r = 0; r < 4; ++r) { best[r] = -3.402823466e+38f; bi[r] = 0; }

    for (int half = 0; half < 2; ++half) {
        #pragma unroll
        for (int nt = 0; nt < 8; ++nt) acc[nt] = (f32x4){0.f, 0.f, 0.f, 0.f};

        for (int kc = 0; kc < 4; ++kc) {
            const int reg = N_WCH + half * 4 + kc;

            float a8[8];
            {
                float4 v0 = *(const float4*)&t[tswz(row, kc * 32 + q * 8)];
                float4 v1 = *(const float4*)&t[tswz(row, kc * 32 + q * 8 + 4)];
                a8[0] = v0.x; a8[1] = v0.y; a8[2] = v0.z; a8[3] = v0.w;
                a8[4] = v1.x; a8[5] = v1.y; a8[6] = v1.z; a8[7] = v1.w;
            }
            split8(a8, ahv, alv);

            PIPE_BARRIER();                 // B1
            STORE_LDS();
            if (reg != 79) ISSUE_LOADS();   // last region: nothing left to fetch
            PIPE_BARRIER();                 // B2

            __builtin_amdgcn_s_setprio(1);
            #pragma unroll
            for (int nt = 0; nt < 8; ++nt) {
                bhv = *(const f16x8*)Bfrag[0][nt][lane];
                blv = *(const f16x8*)Bfrag[1][nt][lane];
                acc[nt] = __builtin_amdgcn_mfma_f32_16x16x32_f16(ahv, bhv, acc[nt], 0, 0, 0);
                acc[nt] = __builtin_amdgcn_mfma_f32_16x16x32_f16(alv, bhv, acc[nt], 0, 0, 0);
                acc[nt] = __builtin_amdgcn_mfma_f32_16x16x32_f16(ahv, blv, acc[nt], 0, 0, 0);
            }
            __builtin_amdgcn_s_setprio(0);
        }

        // ascending p within lane + strict '>' keeps FIRST max (np.argmax)
        #pragma unroll
        for (int nt = 0; nt < 8; ++nt) {
            int p = half * 128 + nt * 16 + m;
            #pragma unroll
            for (int r = 0; r < 4; ++r) {
                float v = acc[nt][r];
                if (v > best[r]) { best[r] = v; bi[r] = p; }
            }
        }
    }

    // reduce over the 16 lanes (cols) sharing each row; tie -> smaller index
    #pragma unroll
    for (int r = 0; r < 4; ++r) {
        #pragma unroll
        for (int off = 1; off < 16; off <<= 1) {
            float ov = __shfl_xor(best[r], off);
            int   oi = __shfl_xor(bi[r], off);
            if (ov > best[r] || (ov == best[r] && oi < bi[r])) { best[r] = ov; bi[r] = oi; }
        }
        if (m == 0)
            assign_out[(size_t)brow + w * 16 + q * 4 + r] = (float)bi[r];
    }
#undef ISSUE_LOADS
#undef STORE_LDS
#undef PIPE_BARRIER
}

// ---------------------------------------------------------------------------
extern "C" void kernel_launch(void* const* d_in, const int* in_sizes, int n_in,
                              void* d_out, int out_size, void* d_ws, size_t ws_size,
                              hipStream_t stream) {
    (void)in_sizes; (void)n_in; (void)out_size; (void)ws_size;

    const float* x      = (const float*)d_in[0];
    const float* protos = (const float*)d_in[1];
    // d_in[2] = grid: uniform knots (j-3)*0.4 - 1, hardcoded
    const float* bw1 = (const float*)d_in[3];
    const float* sw1 = (const float*)d_in[4];
    const float* sc1 = (const float*)d_in[5];
    const float* bw2 = (const float*)d_in[6];
    const float* sw2 = (const float*)d_in[7];
    const float* sc2 = (const float*)d_in[8];

    float* out    = (float*)d_out;
    float* embp   = out;                             // (N,128)
    float* assign = out + (size_t)N_ROWS * HID;      // (N,) as float
    u16*   wpack  = (u16*)d_ws;                      // 1.31 MB packed fragments

    pack_weights<<<dim3((N_WCH + N_PCH) * 4096 / 256), dim3(256), 0, stream>>>(
        bw1, sw1, sc1, bw2, sw2, sc2, protos, wpack);
    kan_fused<<<dim3(N_ROWS / 64), dim3(256), 0, stream>>>(
        x, wpack, embp, assign);
}

// Round 6
// 388.949 us; speedup vs baseline: 1.3077x; 1.0237x over previous
//
#include <hip/hip_runtime.h>
#include <math.h>

typedef unsigned short u16;
typedef _Float16 f16;
typedef __attribute__((ext_vector_type(8))) _Float16 f16x8;
typedef __attribute__((ext_vector_type(2))) _Float16 f16x2;
typedef __attribute__((ext_vector_type(4))) float f32x4;

#define N_ROWS 131072
#define HID 128
#define WS_CH 8192                    // u16 per packed (layer,chunk) region: [hi|lo][nt][lane][c]
#define N_WCH 72                      // 2 layers * 36 chunks
#define N_PCH 8                       // 2 halves * 4 k-chunks of protos

// ---------------------------------------------------------------------------
// f16 split-2 of 8 values, packed: hi = RTZ(v) (11-bit significand, exact via
// mantissa mask), lo = RTZ(v - hi).  |v - hi - lo| <= ~2^-22 |v|.
__device__ __forceinline__ void split8(const float* a8, f16x8& hv, f16x8& lv) {
    union { f16x8 v; f16x2 p[4]; } H, L;
    #pragma unroll
    for (int j = 0; j < 4; ++j) {
        float v0 = a8[2 * j], v1 = a8[2 * j + 1];
        float h0 = __builtin_bit_cast(float, __builtin_bit_cast(unsigned, v0) & 0xFFFFE000u);
        float h1 = __builtin_bit_cast(float, __builtin_bit_cast(unsigned, v1) & 0xFFFFE000u);
        H.p[j] = __builtin_bit_cast(f16x2, __builtin_amdgcn_cvt_pkrtz(v0, v1));           // (hi0,hi1) exactly
        L.p[j] = __builtin_bit_cast(f16x2, __builtin_amdgcn_cvt_pkrtz(v0 - h0, v1 - h1)); // residuals
    }
    hv = H.v; lv = L.v;
}

// cardinal cubic B-spline on uniform knots g[j] = (j-3)*0.4 - 1 -> 8 coef slots
__device__ __forceinline__ void spline8(float xv, float* a8) {
    float s  = (xv + 2.2f) * 2.5f;
    float tf = floorf(s);
    int   tt = (int)tf;
    bool valid = (tt >= 0) && (tt <= 10);
    float kt = (float)(tt - 3) * 0.4f - 1.0f;
    float u  = (xv - kt) * 2.5f;
    float u2 = u * u, u3 = u2 * u;
    float om = 1.0f - u;
    float b3 = u3 * (1.0f / 6.0f);                                   // slot tt
    float b2 = (-3.f * u3 + 3.f * u2 + 3.f * u + 1.f) * (1.0f / 6.0f); // tt-1
    float b1 = (3.f * u3 - 6.f * u2 + 4.f) * (1.0f / 6.0f);          // tt-2
    float b0 = om * om * om * (1.0f / 6.0f);                         // tt-3
    #pragma unroll
    for (int c = 0; c < 8; ++c) {
        int d = tt - c;
        float v = 0.f;
        v = (d == 0) ? b3 : v;
        v = (d == 1) ? b2 : v;
        v = (d == 2) ? b1 : v;
        v = (d == 3) ? b0 : v;
        a8[c] = valid ? v : 0.f;
    }
}

// t-tile XOR swizzle: slot (16B unit) within row XORed with row&31.
// Breaks the stride-128-float same-bank pattern at every access site (<=2-way).
__device__ __forceinline__ int tswz(int r, int c) {
    return (r << 7) + ((((c >> 2) ^ r) & 31) << 2) + (c & 3);
}

// ---------------------------------------------------------------------------
// Pre-pack: weights (spline_w*scaler folded) and protos -> f16 hi/lo in MFMA
// B-fragment order. Proto fragments are PRE-NORMALIZED (1/||p|| folded in).
// ws region r (u16 stride WS_CH):
//   r = l*36 + ch           : layer weights, B[k_local][o]
//   r = 72 + half*4 + kc    : normalized protos, B[k_local][p_local]
// in-region: idx = (nt*64 + kq*16 + n)*8 + c ; hi at +0, lo at +4096.
// Regions 0..79 are consumed strictly sequentially by kan_fused.
// ---------------------------------------------------------------------------
__global__ __launch_bounds__(256)
void pack_weights(const float* __restrict__ bw1, const float* __restrict__ sw1,
                  const float* __restrict__ sc1,
                  const float* __restrict__ bw2, const float* __restrict__ sw2,
                  const float* __restrict__ sc2,
                  const float* __restrict__ protos, u16* __restrict__ ws)
{
    int gid = blockIdx.x * 256 + threadIdx.x;
    if (gid < N_WCH * 4096) {
        int l  = gid / (36 * 4096);
        int r  = gid % (36 * 4096);
        int ch = r / 4096;
        int e  = r % 4096;             // o*32 + k_local
        int o  = e >> 5;
        int kl = e & 31;
        const float* bw = l ? bw2 : bw1;
        const float* sw = l ? sw2 : sw1;
        const float* sc = l ? sc2 : sc1;
        float v;
        if (ch < 4) {
            v = bw[o * HID + ch * 32 + kl];
        } else {
            int i = (ch - 4) * 4 + (kl >> 3);
            v = sw[(o * HID + i) * 8 + (kl & 7)] * sc[o * HID + i];
        }
        f16 hi = (f16)v;
        f16 lo = (f16)(v - (float)hi);
        int nt = o >> 4, n = o & 15, kq = kl >> 3, c = kl & 7;
        size_t base = (size_t)(l * 36 + ch) * WS_CH;
        size_t idx  = ((size_t)nt * 64 + kq * 16 + n) * 8 + c;
        ws[base + idx]        = __builtin_bit_cast(u16, hi);
        ws[base + 4096 + idx] = __builtin_bit_cast(u16, lo);
    } else if (gid < (N_WCH + N_PCH) * 4096) {
        int r  = gid - N_WCH * 4096;
        int hk = r / 4096;             // half*4 + kc
        int e  = r % 4096;             // p_local*32 + kl
        int pl = e >> 5;
        int kl = e & 31;                // == lane&31 (regions are 64-aligned)
        int half = hk >> 2, kc = hk & 3;
        int p = half * 128 + pl;
        // cooperative ||proto_p||^2 over the 32-lane group owning proto p
        const float4 pv = *(const float4*)(protos + (size_t)p * HID + kl * 4);
        float s = pv.x * pv.x + pv.y * pv.y + pv.z * pv.z + pv.w * pv.w;
        #pragma unroll
        for (int off = 1; off < 32; off <<= 1) s += __shfl_xor(s, off);
        float rp = 1.0f / fmaxf(sqrtf(s), 1e-8f);
        float v = protos[(size_t)p * HID + kc * 32 + kl] * rp;
        f16 hi = (f16)v;
        f16 lo = (f16)(v - (float)hi);
        int nt = pl >> 4, n = pl & 15, kq = kl >> 3, c = kl & 7;
        size_t base = (size_t)(N_WCH + hk) * WS_CH;
        size_t idx  = ((size_t)nt * 64 + kq * 16 + n) * 8 + c;
        ws[base + idx]        = __builtin_bit_cast(u16, hi);
        ws[base + 4096 + idx] = __builtin_bit_cast(u16, lo);
    }
}

// ---------------------------------------------------------------------------
// Fused main kernel: x -> KAN layer1 -> KAN layer2 -> emb -> cosine argmax.
// Per block: 128 rows, 4 waves; EACH WAVE OWNS 32 ROWS (two 16-row groups).
// M-register-blocking: one B-fragment read (bhv/blv) feeds MFMAs for BOTH
// row groups -> B LDS-read traffic per row is HALVED vs 16-row waves
// (DS pipe was the computed bottleneck: ~205us of ds_read_b128 at 16 rows).
// 16x16x32 f16 MFMA, 3-product split (ah*bh + al*bh + ah*bl), err <= 2^-22.
//
// Pipeline per epoch (R5-proven):
//   A-prep(2 groups) | B1(lgkm0+bar) | ds_write staged regs | issue loads
//   for s+1 | B2(lgkm0+bar) | 48 MFMA (setprio-wrapped)
// Loads stay in flight across both barriers (no vmcnt drain at barriers).
// LDS = 64 KB t (XOR-swizzled, wave-private 32-row bands) + 16 KB Bfrag
// = 80 KB -> 2 blocks/CU (8 waves). launch_bounds(256,2) -> 256-VGPR budget,
// acc0[8]+acc1[8] (64 regs) fit without spill.
// ---------------------------------------------------------------------------
__global__ __launch_bounds__(256, 2)
void kan_fused(const float* __restrict__ x, const u16* __restrict__ wpack,
               float* __restrict__ emb_out, float* __restrict__ assign_out)
{
    __shared__ float t[128 * 128];         // x -> h -> emb tile (swizzled)
    __shared__ u16   Bfrag[2][8][64][8];   // [hi/lo][nt][lane(kq*16+n)][c]

    const int tid  = threadIdx.x;
    const int lane = tid & 63;
    const int w    = tid >> 6;            // wave 0..3
    const int m    = lane & 15;           // A-row / B-col within 16-tile
    const int q    = lane >> 4;           // 0..3
    const int row0 = w * 32 + m;          // row group 0 (group 1 = +16)
    const int brow = blockIdx.x * 128;

    // per-lane staging pointers (bump by 16 KB per region; imm offsets 0..3072)
    const char* gptr = (const char*)wpack + (size_t)w * 4096 + (size_t)lane * 16;
    uint4* const lptr = (uint4*)&Bfrag[0][0][0][0] + w * 256 + lane;
    uint4 rr0, rr1, rr2, rr3;             // one region in flight

#define ISSUE_LOADS() do {                                                         \
        rr0 = *(const uint4*)(gptr);                                               \
        rr1 = *(const uint4*)(gptr + 1024);                                        \
        rr2 = *(const uint4*)(gptr + 2048);                                        \
        rr3 = *(const uint4*)(gptr + 3072);                                        \
        gptr += 16384;                                                             \
    } while (0)

#define STORE_LDS() do {                                                           \
        lptr[0] = rr0; lptr[64] = rr1; lptr[128] = rr2; lptr[192] = rr3;           \
    } while (0)

    // raw barrier: drain own LDS ops, sync, pin scheduling.
    // NO vmcnt drain -> prefetched global loads survive across it.
#define PIPE_BARRIER() do {                                                        \
        asm volatile("s_waitcnt lgkmcnt(0)" ::: "memory");                         \
        __builtin_amdgcn_s_barrier();                                              \
        __builtin_amdgcn_sched_barrier(0);                                         \
    } while (0)

    ISSUE_LOADS();    // region 0 in flight ASAP

    // ---- stage x tile (wave-private rows: wave w stages rows w*32..+31) ----
    {
        const int m2 = tid >> 1, hf = tid & 1;
        const float4* src = (const float4*)(x + (size_t)(brow + m2) * HID + hf * 64);
        #pragma unroll
        for (int j = 0; j < 16; ++j) {
            float4 v = src[j];
            *(float4*)&t[tswz(m2, hf * 64 + j * 4)] = v;
        }
    }
    // no barrier needed: t rows are wave-private; Bfrag handled by pipe barriers

    f16x8 ah0, al0, ah1, al1, bhv, blv;
    f32x4 acc0[8], acc1[8];

    // ================= two KAN layers =================
    for (int l = 0; l < 2; ++l) {
        #pragma unroll
        for (int nt = 0; nt < 8; ++nt) {
            acc0[nt] = (f32x4){0.f, 0.f, 0.f, 0.f};
            acc1[nt] = (f32x4){0.f, 0.f, 0.f, 0.f};
        }

        for (int ch = 0; ch < 36; ++ch) {
            // ---- A fragments for both row groups ----
            float a80[8], a81[8];
            if (ch < 4) {
                float4 u0 = *(const float4*)&t[tswz(row0, ch * 32 + q * 8)];
                float4 u1 = *(const float4*)&t[tswz(row0, ch * 32 + q * 8 + 4)];
                float4 v0 = *(const float4*)&t[tswz(row0 + 16, ch * 32 + q * 8)];
                float4 v1 = *(const float4*)&t[tswz(row0 + 16, ch * 32 + q * 8 + 4)];
                float xs0[8] = {u0.x, u0.y, u0.z, u0.w, u1.x, u1.y, u1.z, u1.w};
                float xs1[8] = {v0.x, v0.y, v0.z, v0.w, v1.x, v1.y, v1.z, v1.w};
                #pragma unroll
                for (int j = 0; j < 8; ++j) {  // silu via v_exp + v_rcp (~2^-22 rel)
                    a80[j] = xs0[j] * __builtin_amdgcn_rcpf(1.0f + __expf(-xs0[j]));
                    a81[j] = xs1[j] * __builtin_amdgcn_rcpf(1.0f + __expf(-xs1[j]));
                }
            } else {
                spline8(t[tswz(row0,      (ch - 4) * 4 + q)], a80);   // feature i0+q
                spline8(t[tswz(row0 + 16, (ch - 4) * 4 + q)], a81);
            }
            split8(a80, ah0, al0);
            split8(a81, ah1, al1);

            PIPE_BARRIER();     // B1: all waves done reading Bfrag(prev region)
            STORE_LDS();        // waits vmcnt for rr (issued a full epoch ago)
            ISSUE_LOADS();      // next region (71 -> 72 rolls into protos)
            PIPE_BARRIER();     // B2: all waves' ds_writes visible

            // ---- MFMAs: 8 col-tiles x 3 split products x 2 row groups ----
            __builtin_amdgcn_s_setprio(1);
            #pragma unroll
            for (int nt = 0; nt < 8; ++nt) {
                bhv = *(const f16x8*)Bfrag[0][nt][lane];
                blv = *(const f16x8*)Bfrag[1][nt][lane];
                acc0[nt] = __builtin_amdgcn_mfma_f32_16x16x32_f16(ah0, bhv, acc0[nt], 0, 0, 0);
                acc0[nt] = __builtin_amdgcn_mfma_f32_16x16x32_f16(al0, bhv, acc0[nt], 0, 0, 0);
                acc0[nt] = __builtin_amdgcn_mfma_f32_16x16x32_f16(ah0, blv, acc0[nt], 0, 0, 0);
                acc1[nt] = __builtin_amdgcn_mfma_f32_16x16x32_f16(ah1, bhv, acc1[nt], 0, 0, 0);
                acc1[nt] = __builtin_amdgcn_mfma_f32_16x16x32_f16(al1, bhv, acc1[nt], 0, 0, 0);
                acc1[nt] = __builtin_amdgcn_mfma_f32_16x16x32_f16(ah1, blv, acc1[nt], 0, 0, 0);
            }
            __builtin_amdgcn_s_setprio(0);
        }

        // ---- C/D -> t (col = lane&15, row = q*4 + reg); wave-private rows ----
        #pragma unroll
        for (int nt = 0; nt < 8; ++nt)
            #pragma unroll
            for (int r = 0; r < 4; ++r) {
                t[tswz(w * 32 + q * 4 + r,      nt * 16 + m)] = acc0[nt][r];
                t[tswz(w * 32 + 16 + q * 4 + r, nt * 16 + m)] = acc1[nt][r];
            }
        // same-wave LDS program order: no barrier needed between layers
    }

    // ---- emb epilogue: coalesced global write from t (wave-private rows) ----
    {
        const int m2 = tid >> 1, hf = tid & 1;
        float* dst = emb_out + (size_t)(brow + m2) * HID + hf * 64;
        #pragma unroll
        for (int j = 0; j < 16; ++j)
            *(float4*)(dst + j * 4) = *(const float4*)&t[tswz(m2, hf * 64 + j * 4)];
    }

    // ================= cosine-sim argmax =================
    // proto fragments are pre-normalized; row norm is argmax-invariant.
    float best0[4], best1[4]; int bi0[4], bi1[4];
    #pragma unroll
    for (int r = 0; r < 4; ++r) {
        best0[r] = -3.402823466e+38f; bi0[r] = 0;
        best1[r] = -3.402823466e+38f; bi1[r] = 0;
    }

    for (int half = 0; half < 2; ++half) {
        #pragma unroll
        for (int nt = 0; nt < 8; ++nt) {
            acc0[nt] = (f32x4){0.f, 0.f, 0.f, 0.f};
            acc1[nt] = (f32x4){0.f, 0.f, 0.f, 0.f};
        }

        for (int kc = 0; kc < 4; ++kc) {
            const int reg = N_WCH + half * 4 + kc;

            float a80[8], a81[8];
            {
                float4 u0 = *(const float4*)&t[tswz(row0, kc * 32 + q * 8)];
                float4 u1 = *(const float4*)&t[tswz(row0, kc * 32 + q * 8 + 4)];
                float4 v0 = *(const float4*)&t[tswz(row0 + 16, kc * 32 + q * 8)];
                float4 v1 = *(const float4*)&t[tswz(row0 + 16, kc * 32 + q * 8 + 4)];
                a80[0] = u0.x; a80[1] = u0.y; a80[2] = u0.z; a80[3] = u0.w;
                a80[4] = u1.x; a80[5] = u1.y; a80[6] = u1.z; a80[7] = u1.w;
                a81[0] = v0.x; a81[1] = v0.y; a81[2] = v0.z; a81[3] = v0.w;
                a81[4] = v1.x; a81[5] = v1.y; a81[6] = v1.z; a81[7] = v1.w;
            }
            split8(a80, ah0, al0);
            split8(a81, ah1, al1);

            PIPE_BARRIER();                 // B1
            STORE_LDS();
            if (reg != 79) ISSUE_LOADS();   // last region: nothing left to fetch
            PIPE_BARRIER();                 // B2

            __builtin_amdgcn_s_setprio(1);
            #pragma unroll
            for (int nt = 0; nt < 8; ++nt) {
                bhv = *(const f16x8*)Bfrag[0][nt][lane];
                blv = *(const f16x8*)Bfrag[1][nt][lane];
                acc0[nt] = __builtin_amdgcn_mfma_f32_16x16x32_f16(ah0, bhv, acc0[nt], 0, 0, 0);
                acc0[nt] = __builtin_amdgcn_mfma_f32_16x16x32_f16(al0, bhv, acc0[nt], 0, 0, 0);
                acc0[nt] = __builtin_amdgcn_mfma_f32_16x16x32_f16(ah0, blv, acc0[nt], 0, 0, 0);
                acc1[nt] = __builtin_amdgcn_mfma_f32_16x16x32_f16(ah1, bhv, acc1[nt], 0, 0, 0);
                acc1[nt] = __builtin_amdgcn_mfma_f32_16x16x32_f16(al1, bhv, acc1[nt], 0, 0, 0);
                acc1[nt] = __builtin_amdgcn_mfma_f32_16x16x32_f16(ah1, blv, acc1[nt], 0, 0, 0);
            }
            __builtin_amdgcn_s_setprio(0);
        }

        // ascending p within lane + strict '>' keeps FIRST max (np.argmax)
        #pragma unroll
        for (int nt = 0; nt < 8; ++nt) {
            int p = half * 128 + nt * 16 + m;
            #pragma unroll
            for (int r = 0; r < 4; ++r) {
                float v0 = acc0[nt][r];
                if (v0 > best0[r]) { best0[r] = v0; bi0[r] = p; }
                float v1 = acc1[nt][r];
                if (v1 > best1[r]) { best1[r] = v1; bi1[r] = p; }
            }
        }
    }

    // reduce over the 16 lanes (cols) sharing each row; tie -> smaller index
    #pragma unroll
    for (int r = 0; r < 4; ++r) {
        #pragma unroll
        for (int off = 1; off < 16; off <<= 1) {
            float ov0 = __shfl_xor(best0[r], off);
            int   oi0 = __shfl_xor(bi0[r], off);
            if (ov0 > best0[r] || (ov0 == best0[r] && oi0 < bi0[r])) { best0[r] = ov0; bi0[r] = oi0; }
            float ov1 = __shfl_xor(best1[r], off);
            int   oi1 = __shfl_xor(bi1[r], off);
            if (ov1 > best1[r] || (ov1 == best1[r] && oi1 < bi1[r])) { best1[r] = ov1; bi1[r] = oi1; }
        }
        if (m == 0) {
            assign_out[(size_t)brow + w * 32 + q * 4 + r]      = (float)bi0[r];
            assign_out[(size_t)brow + w * 32 + 16 + q * 4 + r] = (float)bi1[r];
        }
    }
#undef ISSUE_LOADS
#undef STORE_LDS
#undef PIPE_BARRIER
}

// ---------------------------------------------------------------------------
extern "C" void kernel_launch(void* const* d_in, const int* in_sizes, int n_in,
                              void* d_out, int out_size, void* d_ws, size_t ws_size,
                              hipStream_t stream) {
    (void)in_sizes; (void)n_in; (void)out_size; (void)ws_size;

    const float* x      = (const float*)d_in[0];
    const float* protos = (const float*)d_in[1];
    // d_in[2] = grid: uniform knots (j-3)*0.4 - 1, hardcoded
    const float* bw1 = (const float*)d_in[3];
    const float* sw1 = (const float*)d_in[4];
    const float* sc1 = (const float*)d_in[5];
    const float* bw2 = (const float*)d_in[6];
    const float* sw2 = (const float*)d_in[7];
    const float* sc2 = (const float*)d_in[8];

    float* out    = (float*)d_out;
    float* embp   = out;                             // (N,128)
    float* assign = out + (size_t)N_ROWS * HID;      // (N,) as float
    u16*   wpack  = (u16*)d_ws;                      // 1.31 MB packed fragments

    pack_weights<<<dim3((N_WCH + N_PCH) * 4096 / 256), dim3(256), 0, stream>>>(
        bw1, sw1, sc1, bw2, sw2, sc2, protos, wpack);
    kan_fused<<<dim3(N_ROWS / 128), dim3(256), 0, stream>>>(
        x, wpack, embp, assign);
}

// Round 7
// 383.583 us; speedup vs baseline: 1.3260x; 1.0140x over previous
//
#include <hip/hip_runtime.h>
#include <math.h>

typedef unsigned short u16;
typedef _Float16 f16;
typedef __attribute__((ext_vector_type(8))) _Float16 f16x8;
typedef __attribute__((ext_vector_type(2))) _Float16 f16x2;
typedef __attribute__((ext_vector_type(4))) float f32x4;

#define N_ROWS 131072
#define HID 128
#define WS_CH 8192                    // u16 per packed (layer,chunk) region: [hi|lo][nt][lane][c]
#define N_WCH 72                      // 2 layers * 36 chunks
#define N_PCH 8                       // 2 halves * 4 k-chunks of protos

// ---------------------------------------------------------------------------
// f16 split-2 of 8 values, packed: hi = RTZ(v) (11-bit significand, exact via
// mantissa mask), lo = RTZ(v - hi).  |v - hi - lo| <= ~2^-22 |v|.
__device__ __forceinline__ void split8(const float* a8, f16x8& hv, f16x8& lv) {
    union { f16x8 v; f16x2 p[4]; } H, L;
    #pragma unroll
    for (int j = 0; j < 4; ++j) {
        float v0 = a8[2 * j], v1 = a8[2 * j + 1];
        float h0 = __builtin_bit_cast(float, __builtin_bit_cast(unsigned, v0) & 0xFFFFE000u);
        float h1 = __builtin_bit_cast(float, __builtin_bit_cast(unsigned, v1) & 0xFFFFE000u);
        H.p[j] = __builtin_bit_cast(f16x2, __builtin_amdgcn_cvt_pkrtz(v0, v1));           // (hi0,hi1) exactly
        L.p[j] = __builtin_bit_cast(f16x2, __builtin_amdgcn_cvt_pkrtz(v0 - h0, v1 - h1)); // residuals
    }
    hv = H.v; lv = L.v;
}

__device__ __forceinline__ float silu1(float v) {
    return v * __builtin_amdgcn_rcpf(1.0f + __expf(-v));   // ~2^-22 rel
}

// cardinal cubic B-spline on uniform knots g[j] = (j-3)*0.4 - 1 -> 8 coef slots
__device__ __forceinline__ void spline8(float xv, float* a8) {
    float s  = (xv + 2.2f) * 2.5f;
    float tf = floorf(s);
    int   tt = (int)tf;
    bool valid = (tt >= 0) && (tt <= 10);
    float kt = (float)(tt - 3) * 0.4f - 1.0f;
    float u  = (xv - kt) * 2.5f;
    float u2 = u * u, u3 = u2 * u;
    float om = 1.0f - u;
    float b3 = u3 * (1.0f / 6.0f);                                   // slot tt
    float b2 = (-3.f * u3 + 3.f * u2 + 3.f * u + 1.f) * (1.0f / 6.0f); // tt-1
    float b1 = (3.f * u3 - 6.f * u2 + 4.f) * (1.0f / 6.0f);          // tt-2
    float b0 = om * om * om * (1.0f / 6.0f);                         // tt-3
    #pragma unroll
    for (int c = 0; c < 8; ++c) {
        int d = tt - c;
        float v = 0.f;
        v = (d == 0) ? b3 : v;
        v = (d == 1) ? b2 : v;
        v = (d == 2) ? b1 : v;
        v = (d == 3) ? b0 : v;
        a8[c] = valid ? v : 0.f;
    }
}

// t-tile XOR swizzle: slot (16B unit) within row XORed with row&31.
// Breaks the stride-128-float same-bank pattern at every access site (<=2-way).
__device__ __forceinline__ int tswz(int r, int c) {
    return (r << 7) + ((((c >> 2) ^ r) & 31) << 2) + (c & 3);
}

// ---------------------------------------------------------------------------
// Pre-pack: weights (spline_w*scaler folded) and protos -> f16 hi/lo in MFMA
// B-fragment order. Proto fragments are PRE-NORMALIZED (1/||p|| folded in).
// ws region r (u16 stride WS_CH):
//   r = l*36 + ch           : layer weights, B[k_local][o]
//   r = 72 + half*4 + kc    : normalized protos, B[k_local][p_local]
// in-region: idx = (nt*64 + kq*16 + n)*8 + c ; hi at +0, lo at +4096.
// Regions 0..79 are consumed strictly sequentially by kan_fused.
// ---------------------------------------------------------------------------
__global__ __launch_bounds__(256)
void pack_weights(const float* __restrict__ bw1, const float* __restrict__ sw1,
                  const float* __restrict__ sc1,
                  const float* __restrict__ bw2, const float* __restrict__ sw2,
                  const float* __restrict__ sc2,
                  const float* __restrict__ protos, u16* __restrict__ ws)
{
    int gid = blockIdx.x * 256 + threadIdx.x;
    if (gid < N_WCH * 4096) {
        int l  = gid / (36 * 4096);
        int r  = gid % (36 * 4096);
        int ch = r / 4096;
        int e  = r % 4096;             // o*32 + k_local
        int o  = e >> 5;
        int kl = e & 31;
        const float* bw = l ? bw2 : bw1;
        const float* sw = l ? sw2 : sw1;
        const float* sc = l ? sc2 : sc1;
        float v;
        if (ch < 4) {
            v = bw[o * HID + ch * 32 + kl];
        } else {
            int i = (ch - 4) * 4 + (kl >> 3);
            v = sw[(o * HID + i) * 8 + (kl & 7)] * sc[o * HID + i];
        }
        f16 hi = (f16)v;
        f16 lo = (f16)(v - (float)hi);
        int nt = o >> 4, n = o & 15, kq = kl >> 3, c = kl & 7;
        size_t base = (size_t)(l * 36 + ch) * WS_CH;
        size_t idx  = ((size_t)nt * 64 + kq * 16 + n) * 8 + c;
        ws[base + idx]        = __builtin_bit_cast(u16, hi);
        ws[base + 4096 + idx] = __builtin_bit_cast(u16, lo);
    } else if (gid < (N_WCH + N_PCH) * 4096) {
        int r  = gid - N_WCH * 4096;
        int hk = r / 4096;             // half*4 + kc
        int e  = r % 4096;             // p_local*32 + kl
        int pl = e >> 5;
        int kl = e & 31;                // == lane&31 (regions are 64-aligned)
        int half = hk >> 2, kc = hk & 3;
        int p = half * 128 + pl;
        // cooperative ||proto_p||^2 over the 32-lane group owning proto p
        const float4 pv = *(const float4*)(protos + (size_t)p * HID + kl * 4);
        float s = pv.x * pv.x + pv.y * pv.y + pv.z * pv.z + pv.w * pv.w;
        #pragma unroll
        for (int off = 1; off < 32; off <<= 1) s += __shfl_xor(s, off);
        float rp = 1.0f / fmaxf(sqrtf(s), 1e-8f);
        float v = protos[(size_t)p * HID + kc * 32 + kl] * rp;
        f16 hi = (f16)v;
        f16 lo = (f16)(v - (float)hi);
        int nt = pl >> 4, n = pl & 15, kq = kl >> 3, c = kl & 7;
        size_t base = (size_t)(N_WCH + hk) * WS_CH;
        size_t idx  = ((size_t)nt * 64 + kq * 16 + n) * 8 + c;
        ws[base + idx]        = __builtin_bit_cast(u16, hi);
        ws[base + 4096 + idx] = __builtin_bit_cast(u16, lo);
    }
}

// ---------------------------------------------------------------------------
// Fused main kernel: x -> KAN layer1 -> KAN layer2 -> emb -> cosine argmax.
// Per block: 128 rows, 4 waves; EACH WAVE OWNS 32 ROWS (two 16-row groups).
// M-register-blocking: one B-fragment read (bhv/blv) feeds MFMAs for BOTH
// row groups -> B LDS-read traffic per row HALVED vs 16-row waves.
// 16x16x32 f16 MFMA, 3-product split (ah*bh + al*bh + ah*bl), err <= 2^-22.
//
// R7 fix vs R6: A-prep register peak removed. The two row groups are
// processed SEQUENTIALLY through one a8[8] buffer with split8 immediately
// after each (R6 held a80+a81+xs0+xs1 = 32 transient VGPRs live at once ->
// ~2-3 dwords/epoch spilled to scratch -> +185 MB HBM writes, +12us).
//
// Pipeline per epoch:
//   A-prep(g0|split|g1|split) | B1(lgkm0+bar) | ds_write staged regs |
//   issue loads for s+1 | B2(lgkm0+bar) | 48 MFMA (setprio-wrapped)
// Loads stay in flight across both barriers (no vmcnt drain at barriers).
// LDS = 64 KB t (XOR-swizzled, wave-private 32-row bands) + 16 KB Bfrag
// = 80 KB -> 2 blocks/CU (8 waves).
// ---------------------------------------------------------------------------
__global__ __launch_bounds__(256, 2)
void kan_fused(const float* __restrict__ x, const u16* __restrict__ wpack,
               float* __restrict__ emb_out, float* __restrict__ assign_out)
{
    __shared__ float t[128 * 128];         // x -> h -> emb tile (swizzled)
    __shared__ u16   Bfrag[2][8][64][8];   // [hi/lo][nt][lane(kq*16+n)][c]

    const int tid  = threadIdx.x;
    const int lane = tid & 63;
    const int w    = tid >> 6;            // wave 0..3
    const int m    = lane & 15;           // A-row / B-col within 16-tile
    const int q    = lane >> 4;           // 0..3
    const int row0 = w * 32 + m;          // row group 0 (group 1 = +16)
    const int brow = blockIdx.x * 128;

    // per-lane staging pointers (bump by 16 KB per region; imm offsets 0..3072)
    const char* gptr = (const char*)wpack + (size_t)w * 4096 + (size_t)lane * 16;
    uint4* const lptr = (uint4*)&Bfrag[0][0][0][0] + w * 256 + lane;
    uint4 rr0, rr1, rr2, rr3;             // one region in flight

#define ISSUE_LOADS() do {                                                         \
        rr0 = *(const uint4*)(gptr);                                               \
        rr1 = *(const uint4*)(gptr + 1024);                                        \
        rr2 = *(const uint4*)(gptr + 2048);                                        \
        rr3 = *(const uint4*)(gptr + 3072);                                        \
        gptr += 16384;                                                             \
    } while (0)

#define STORE_LDS() do {                                                           \
        lptr[0] = rr0; lptr[64] = rr1; lptr[128] = rr2; lptr[192] = rr3;           \
    } while (0)

    // raw barrier: drain own LDS ops, sync, pin scheduling.
    // NO vmcnt drain -> prefetched global loads survive across it.
#define PIPE_BARRIER() do {                                                        \
        asm volatile("s_waitcnt lgkmcnt(0)" ::: "memory");                         \
        __builtin_amdgcn_s_barrier();                                              \
        __builtin_amdgcn_sched_barrier(0);                                         \
    } while (0)

    ISSUE_LOADS();    // region 0 in flight ASAP

    // ---- stage x tile (wave-private rows: wave w stages rows w*32..+31) ----
    {
        const int m2 = tid >> 1, hf = tid & 1;
        const float4* src = (const float4*)(x + (size_t)(brow + m2) * HID + hf * 64);
        #pragma unroll
        for (int j = 0; j < 16; ++j) {
            float4 v = src[j];
            *(float4*)&t[tswz(m2, hf * 64 + j * 4)] = v;
        }
    }
    // no barrier needed: t rows are wave-private; Bfrag handled by pipe barriers

    f16x8 ah0, al0, ah1, al1, bhv, blv;
    f32x4 acc0[8], acc1[8];

    // ================= two KAN layers =================
    for (int l = 0; l < 2; ++l) {
        #pragma unroll
        for (int nt = 0; nt < 8; ++nt) {
            acc0[nt] = (f32x4){0.f, 0.f, 0.f, 0.f};
            acc1[nt] = (f32x4){0.f, 0.f, 0.f, 0.f};
        }

        for (int ch = 0; ch < 36; ++ch) {
            // ---- A fragments: groups processed SEQUENTIALLY via one a8 ----
            float a8[8];
            if (ch < 4) {
                float4 u0 = *(const float4*)&t[tswz(row0, ch * 32 + q * 8)];
                float4 u1 = *(const float4*)&t[tswz(row0, ch * 32 + q * 8 + 4)];
                a8[0] = silu1(u0.x); a8[1] = silu1(u0.y);
                a8[2] = silu1(u0.z); a8[3] = silu1(u0.w);
                a8[4] = silu1(u1.x); a8[5] = silu1(u1.y);
                a8[6] = silu1(u1.z); a8[7] = silu1(u1.w);
            } else {
                spline8(t[tswz(row0, (ch - 4) * 4 + q)], a8);   // feature i0+q
            }
            split8(a8, ah0, al0);
            if (ch < 4) {
                float4 u0 = *(const float4*)&t[tswz(row0 + 16, ch * 32 + q * 8)];
                float4 u1 = *(const float4*)&t[tswz(row0 + 16, ch * 32 + q * 8 + 4)];
                a8[0] = silu1(u0.x); a8[1] = silu1(u0.y);
                a8[2] = silu1(u0.z); a8[3] = silu1(u0.w);
                a8[4] = silu1(u1.x); a8[5] = silu1(u1.y);
                a8[6] = silu1(u1.z); a8[7] = silu1(u1.w);
            } else {
                spline8(t[tswz(row0 + 16, (ch - 4) * 4 + q)], a8);
            }
            split8(a8, ah1, al1);

            PIPE_BARRIER();     // B1: all waves done reading Bfrag(prev region)
            STORE_LDS();        // waits vmcnt for rr (issued a full epoch ago)
            ISSUE_LOADS();      // next region (71 -> 72 rolls into protos)
            PIPE_BARRIER();     // B2: all waves' ds_writes visible

            // ---- MFMAs: 8 col-tiles x 3 split products x 2 row groups ----
            __builtin_amdgcn_s_setprio(1);
            #pragma unroll
            for (int nt = 0; nt < 8; ++nt) {
                bhv = *(const f16x8*)Bfrag[0][nt][lane];
                blv = *(const f16x8*)Bfrag[1][nt][lane];
                acc0[nt] = __builtin_amdgcn_mfma_f32_16x16x32_f16(ah0, bhv, acc0[nt], 0, 0, 0);
                acc0[nt] = __builtin_amdgcn_mfma_f32_16x16x32_f16(al0, bhv, acc0[nt], 0, 0, 0);
                acc0[nt] = __builtin_amdgcn_mfma_f32_16x16x32_f16(ah0, blv, acc0[nt], 0, 0, 0);
                acc1[nt] = __builtin_amdgcn_mfma_f32_16x16x32_f16(ah1, bhv, acc1[nt], 0, 0, 0);
                acc1[nt] = __builtin_amdgcn_mfma_f32_16x16x32_f16(al1, bhv, acc1[nt], 0, 0, 0);
                acc1[nt] = __builtin_amdgcn_mfma_f32_16x16x32_f16(ah1, blv, acc1[nt], 0, 0, 0);
            }
            __builtin_amdgcn_s_setprio(0);
        }

        // ---- C/D -> t (col = lane&15, row = q*4 + reg); wave-private rows ----
        #pragma unroll
        for (int nt = 0; nt < 8; ++nt)
            #pragma unroll
            for (int r = 0; r < 4; ++r) {
                t[tswz(w * 32 + q * 4 + r,      nt * 16 + m)] = acc0[nt][r];
                t[tswz(w * 32 + 16 + q * 4 + r, nt * 16 + m)] = acc1[nt][r];
            }
        // same-wave LDS program order: no barrier needed between layers
    }

    // ---- emb epilogue: coalesced global write from t (wave-private rows) ----
    {
        const int m2 = tid >> 1, hf = tid & 1;
        float* dst = emb_out + (size_t)(brow + m2) * HID + hf * 64;
        #pragma unroll
        for (int j = 0; j < 16; ++j)
            *(float4*)(dst + j * 4) = *(const float4*)&t[tswz(m2, hf * 64 + j * 4)];
    }

    // ================= cosine-sim argmax =================
    // proto fragments are pre-normalized; row norm is argmax-invariant.
    float best0[4], best1[4]; int bi0[4], bi1[4];
    #pragma unroll
    for (int r = 0; r < 4; ++r) {
        best0[r] = -3.402823466e+38f; bi0[r] = 0;
        best1[r] = -3.402823466e+38f; bi1[r] = 0;
    }

    for (int half = 0; half < 2; ++half) {
        #pragma unroll
        for (int nt = 0; nt < 8; ++nt) {
            acc0[nt] = (f32x4){0.f, 0.f, 0.f, 0.f};
            acc1[nt] = (f32x4){0.f, 0.f, 0.f, 0.f};
        }

        for (int kc = 0; kc < 4; ++kc) {
            const int reg = N_WCH + half * 4 + kc;

            // ---- A fragments: groups sequential via one a8 ----
            float a8[8];
            {
                float4 u0 = *(const float4*)&t[tswz(row0, kc * 32 + q * 8)];
                float4 u1 = *(const float4*)&t[tswz(row0, kc * 32 + q * 8 + 4)];
                a8[0] = u0.x; a8[1] = u0.y; a8[2] = u0.z; a8[3] = u0.w;
                a8[4] = u1.x; a8[5] = u1.y; a8[6] = u1.z; a8[7] = u1.w;
            }
            split8(a8, ah0, al0);
            {
                float4 u0 = *(const float4*)&t[tswz(row0 + 16, kc * 32 + q * 8)];
                float4 u1 = *(const float4*)&t[tswz(row0 + 16, kc * 32 + q * 8 + 4)];
                a8[0] = u0.x; a8[1] = u0.y; a8[2] = u0.z; a8[3] = u0.w;
                a8[4] = u1.x; a8[5] = u1.y; a8[6] = u1.z; a8[7] = u1.w;
            }
            split8(a8, ah1, al1);

            PIPE_BARRIER();                 // B1
            STORE_LDS();
            if (reg != 79) ISSUE_LOADS();   // last region: nothing left to fetch
            PIPE_BARRIER();                 // B2

            __builtin_amdgcn_s_setprio(1);
            #pragma unroll
            for (int nt = 0; nt < 8; ++nt) {
                bhv = *(const f16x8*)Bfrag[0][nt][lane];
                blv = *(const f16x8*)Bfrag[1][nt][lane];
                acc0[nt] = __builtin_amdgcn_mfma_f32_16x16x32_f16(ah0, bhv, acc0[nt], 0, 0, 0);
                acc0[nt] = __builtin_amdgcn_mfma_f32_16x16x32_f16(al0, bhv, acc0[nt], 0, 0, 0);
                acc0[nt] = __builtin_amdgcn_mfma_f32_16x16x32_f16(ah0, blv, acc0[nt], 0, 0, 0);
                acc1[nt] = __builtin_amdgcn_mfma_f32_16x16x32_f16(ah1, bhv, acc1[nt], 0, 0, 0);
                acc1[nt] = __builtin_amdgcn_mfma_f32_16x16x32_f16(al1, bhv, acc1[nt], 0, 0, 0);
                acc1[nt] = __builtin_amdgcn_mfma_f32_16x16x32_f16(ah1, blv, acc1[nt], 0, 0, 0);
            }
            __builtin_amdgcn_s_setprio(0);
        }

        // ascending p within lane + strict '>' keeps FIRST max (np.argmax)
        #pragma unroll
        for (int nt = 0; nt < 8; ++nt) {
            int p = half * 128 + nt * 16 + m;
            #pragma unroll
            for (int r = 0; r < 4; ++r) {
                float v0 = acc0[nt][r];
                if (v0 > best0[r]) { best0[r] = v0; bi0[r] = p; }
                float v1 = acc1[nt][r];
                if (v1 > best1[r]) { best1[r] = v1; bi1[r] = p; }
            }
        }
    }

    // reduce over the 16 lanes (cols) sharing each row; tie -> smaller index
    #pragma unroll
    for (int r = 0; r < 4; ++r) {
        #pragma unroll
        for (int off = 1; off < 16; off <<= 1) {
            float ov0 = __shfl_xor(best0[r], off);
            int   oi0 = __shfl_xor(bi0[r], off);
            if (ov0 > best0[r] || (ov0 == best0[r] && oi0 < bi0[r])) { best0[r] = ov0; bi0[r] = oi0; }
            float ov1 = __shfl_xor(best1[r], off);
            int   oi1 = __shfl_xor(bi1[r], off);
            if (ov1 > best1[r] || (ov1 == best1[r] && oi1 < bi1[r])) { best1[r] = ov1; bi1[r] = oi1; }
        }
        if (m == 0) {
            assign_out[(size_t)brow + w * 32 + q * 4 + r]      = (float)bi0[r];
            assign_out[(size_t)brow + w * 32 + 16 + q * 4 + r] = (float)bi1[r];
        }
    }
#undef ISSUE_LOADS
#undef STORE_LDS
#undef PIPE_BARRIER
}

// ---------------------------------------------------------------------------
extern "C" void kernel_launch(void* const* d_in, const int* in_sizes, int n_in,
                              void* d_out, int out_size, void* d_ws, size_t ws_size,
                              hipStream_t stream) {
    (void)in_sizes; (void)n_in; (void)out_size; (void)ws_size;

    const float* x      = (const float*)d_in[0];
    const float* protos = (const float*)d_in[1];
    // d_in[2] = grid: uniform knots (j-3)*0.4 - 1, hardcoded
    const float* bw1 = (const float*)d_in[3];
    const float* sw1 = (const float*)d_in[4];
    const float* sc1 = (const float*)d_in[5];
    const float* bw2 = (const float*)d_in[6];
    const float* sw2 = (const float*)d_in[7];
    const float* sc2 = (const float*)d_in[8];

    float* out    = (float*)d_out;
    float* embp   = out;                             // (N,128)
    float* assign = out + (size_t)N_ROWS * HID;      // (N,) as float
    u16*   wpack  = (u16*)d_ws;                      // 1.31 MB packed fragments

    pack_weights<<<dim3((N_WCH + N_PCH) * 4096 / 256), dim3(256), 0, stream>>>(
        bw1, sw1, sc1, bw2, sw2, sc2, protos, wpack);
    kan_fused<<<dim3(N_ROWS / 128), dim3(256), 0, stream>>>(
        x, wpack, embp, assign);
}